// Round 1
// baseline (129.095 us; speedup 1.0000x reference)
//
#include <hip/hip_runtime.h>
#include <hip/hip_bf16.h>

#define BB 4
#define QQ 512
#define MM 8192
#define DD 8
#define EE 512
#define SS 256

using f32x4  = __attribute__((ext_vector_type(4))) float;
using bf16x8 = __attribute__((ext_vector_type(8))) short;

__device__ __forceinline__ unsigned short f2bf(float f) {
  union { float f; unsigned int u; } v; v.f = f;
  unsigned int r = v.u + 0x7fffu + ((v.u >> 16) & 1u);
  return (unsigned short)(r >> 16);
}

// ---------------------------------------------------------------------------
// K1: affinity + row softmax -> normalized bf16 weights (B,Q,M)
// grid = B*Q/QT blocks, 512 threads; each thread owns 16 m's per query pair.
// ---------------------------------------------------------------------------
#define QT 2
#define K1_THREADS 512
#define K1_ITERS (MM / K1_THREADS)   // 16

__global__ __launch_bounds__(512) void k_aff(
    const float* __restrict__ loc, const float* __restrict__ locsd,
    const float* __restrict__ mloc, const float* __restrict__ msd,
    unsigned short* __restrict__ wts)
{
  const int blk = blockIdx.x;
  const int b  = blk / (QQ / QT);
  const int q0 = (blk % (QQ / QT)) * QT;
  const int t  = threadIdx.x;

  float lx[QT][DD], ls2[QT][DD];
#pragma unroll
  for (int qi = 0; qi < QT; ++qi)
#pragma unroll
    for (int d = 0; d < DD; ++d) {
      const int base = ((b * QQ) + q0 + qi) * DD + d;
      lx[qi][d] = loc[base];
      float s = locsd[base];
      ls2[qi][d] = s * s;
    }

  const float4* ml4 = reinterpret_cast<const float4*>(mloc + (size_t)b * MM * DD);
  const float4* ms4 = reinterpret_cast<const float4*>(msd  + (size_t)b * MM * DD);

  float la[QT][K1_ITERS];
  float mx[QT];
#pragma unroll
  for (int qi = 0; qi < QT; ++qi) mx[qi] = -3.4e38f;

#pragma unroll
  for (int i = 0; i < K1_ITERS; ++i) {
    const int m = i * K1_THREADS + t;
    float4 a0 = ml4[2 * m], a1 = ml4[2 * m + 1];
    float4 s0 = ms4[2 * m], s1 = ms4[2 * m + 1];
    float mlv[DD] = {a0.x, a0.y, a0.z, a0.w, a1.x, a1.y, a1.z, a1.w};
    float msv[DD] = {s0.x, s0.y, s0.z, s0.w, s1.x, s1.y, s1.z, s1.w};
    float ms2[DD];
#pragma unroll
    for (int d = 0; d < DD; ++d) ms2[d] = msv[d] * msv[d];
#pragma unroll
    for (int qi = 0; qi < QT; ++qi) {
      float ssum = 0.f, p = 1.f;
#pragma unroll
      for (int d = 0; d < DD; ++d) {
        float v  = ls2[qi][d] + ms2[d];
        float r  = __builtin_amdgcn_rcpf(v + 1e-8f);
        float dd0 = lx[qi][d] - mlv[d];
        float tt = dd0 * dd0 * r;
        ssum = __builtin_fmaf(tt, tt, ssum);
        p *= v;                       // sum(log var) == log(prod var): 1 log not 8
      }
      float lav = -0.5f * ssum - __logf(p);   // const -0.5*log(2pi)*D cancels in softmax
      la[qi][i] = lav;
      mx[qi] = fmaxf(mx[qi], lav);
    }
  }

  __shared__ float red[QT][8];
  const int wv = t >> 6;
#pragma unroll
  for (int qi = 0; qi < QT; ++qi)
#pragma unroll
    for (int off = 32; off; off >>= 1)
      mx[qi] = fmaxf(mx[qi], __shfl_xor(mx[qi], off, 64));
  if ((t & 63) == 0) { red[0][wv] = mx[0]; red[1][wv] = mx[1]; }
  __syncthreads();
#pragma unroll
  for (int qi = 0; qi < QT; ++qi) {
    float m2 = red[qi][0];
#pragma unroll
    for (int w = 1; w < 8; ++w) m2 = fmaxf(m2, red[qi][w]);
    mx[qi] = m2;
  }

  float sm[QT] = {0.f, 0.f};
#pragma unroll
  for (int i = 0; i < K1_ITERS; ++i)
#pragma unroll
    for (int qi = 0; qi < QT; ++qi) {
      float e = __expf(la[qi][i] - mx[qi]);
      la[qi][i] = e;
      sm[qi] += e;
    }
  __syncthreads();   // done reading red (max) before overwrite
#pragma unroll
  for (int qi = 0; qi < QT; ++qi)
#pragma unroll
    for (int off = 32; off; off >>= 1)
      sm[qi] += __shfl_xor(sm[qi], off, 64);
  if ((t & 63) == 0) { red[0][wv] = sm[0]; red[1][wv] = sm[1]; }
  __syncthreads();
  float inv[QT];
#pragma unroll
  for (int qi = 0; qi < QT; ++qi) {
    float s = 0.f;
#pragma unroll
    for (int w = 0; w < 8; ++w) s += red[qi][w];
    inv[qi] = 1.0f / s;
  }

#pragma unroll
  for (int i = 0; i < K1_ITERS; ++i) {
    const int m = i * K1_THREADS + t;
#pragma unroll
    for (int qi = 0; qi < QT; ++qi)
      wts[((size_t)(b * QQ + q0 + qi)) * MM + m] = f2bf(la[qi][i] * inv[qi]);
  }
}

// ---------------------------------------------------------------------------
// K2: projT[b][s][m] = sum_e W[s][e] * V[b][m][e]   (bf16 out, fp32 acc MFMA)
// tile: 256(s) x 128(m), BK=64, 512 threads = 8 waves (4x2 of 64x64)
// ---------------------------------------------------------------------------
#define P_BM 256
#define P_BN 128
#define P_BK 64

__global__ __launch_bounds__(512) void k_proj(
    const float* __restrict__ V, const float* __restrict__ W,
    unsigned short* __restrict__ projT)
{
  const int m0 = blockIdx.x * P_BN;
  const int b  = blockIdx.y;
  const int t  = threadIdx.x;
  const int lane = t & 63;
  const int wv = t >> 6;
  const int wr = wv >> 1;   // 0..3 (s quadrant)
  const int wc = wv & 1;    // 0..1 (m quadrant)

  __shared__ short lA[P_BM * P_BK];   // 32KB, XOR-swizzled
  __shared__ short lB[P_BN * P_BK];   // 16KB

  f32x4 acc[4][4] = {};

  const float* Vp = V + (size_t)b * MM * EE;

  for (int k0 = 0; k0 < EE; k0 += P_BK) {
    __syncthreads();
    // stage A = W (256 x 64 window), convert f32->bf16
#pragma unroll
    for (int j = 0; j < 8; ++j) {
      int e0 = (j * 512 + t) * 4;
      int row = e0 >> 6, k = e0 & 63;
      float4 src = *reinterpret_cast<const float4*>(&W[row * EE + k0 + k]);
      int idx = (row * P_BK + k) ^ ((row & 7) << 3);
      ushort4 dv; dv.x = f2bf(src.x); dv.y = f2bf(src.y); dv.z = f2bf(src.z); dv.w = f2bf(src.w);
      *reinterpret_cast<ushort4*>(&lA[idx]) = dv;
    }
    // stage B = V rows m0..m0+127 (128 x 64 window)
#pragma unroll
    for (int j = 0; j < 4; ++j) {
      int e0 = (j * 512 + t) * 4;
      int row = e0 >> 6, k = e0 & 63;
      float4 src = *reinterpret_cast<const float4*>(&Vp[(size_t)(m0 + row) * EE + k0 + k]);
      int idx = (row * P_BK + k) ^ ((row & 7) << 3);
      ushort4 dv; dv.x = f2bf(src.x); dv.y = f2bf(src.y); dv.z = f2bf(src.z); dv.w = f2bf(src.w);
      *reinterpret_cast<ushort4*>(&lB[idx]) = dv;
    }
    __syncthreads();
#pragma unroll
    for (int kk = 0; kk < 2; ++kk) {
      const int kofs = kk * 32 + (lane >> 4) * 8;
      const int r15 = lane & 15;
      bf16x8 af[4], bfv[4];
#pragma unroll
      for (int mi = 0; mi < 4; ++mi) {
        int row = wr * 64 + mi * 16 + r15;
        af[mi] = *reinterpret_cast<const bf16x8*>(&lA[(row * P_BK + kofs) ^ ((row & 7) << 3)]);
      }
#pragma unroll
      for (int ni = 0; ni < 4; ++ni) {
        int row = wc * 64 + ni * 16 + r15;
        bfv[ni] = *reinterpret_cast<const bf16x8*>(&lB[(row * P_BK + kofs) ^ ((row & 7) << 3)]);
      }
#pragma unroll
      for (int mi = 0; mi < 4; ++mi)
#pragma unroll
        for (int ni = 0; ni < 4; ++ni)
          acc[mi][ni] = __builtin_amdgcn_mfma_f32_16x16x32_bf16(af[mi], bfv[ni], acc[mi][ni], 0, 0, 0);
    }
  }

  unsigned short* outp = projT + (size_t)b * SS * MM;
  const int fr = (lane >> 4) * 4;
  const int fc = lane & 15;
#pragma unroll
  for (int mi = 0; mi < 4; ++mi)
#pragma unroll
    for (int ni = 0; ni < 4; ++ni)
#pragma unroll
      for (int r = 0; r < 4; ++r) {
        int s = wr * 64 + mi * 16 + fr + r;
        int m = m0 + wc * 64 + ni * 16 + fc;
        outp[(size_t)s * MM + m] = f2bf(acc[mi][ni][r]);
      }
}

// ---------------------------------------------------------------------------
// K3: out[b][q][s] += sum_m wts[b][q][m] * projT[b][s][m]  (K-split 8, atomicAdd)
// tile 128x128, BK=64, 256 threads = 4 waves (2x2 of 64x64)
// ---------------------------------------------------------------------------
#define G_BM 128
#define G_BN 128
#define G_BK 64
#define G_KSPLIT 8

__global__ __launch_bounds__(256) void k_wgemm(
    const unsigned short* __restrict__ wts,
    const unsigned short* __restrict__ projT,
    float* __restrict__ out)
{
  const int tile = blockIdx.x;          // 0..7 : 4 q-tiles x 2 s-tiles
  const int ks   = blockIdx.y;          // 0..7
  const int b    = blockIdx.z;
  const int q0 = (tile >> 1) * G_BM;
  const int s0 = (tile & 1) * G_BN;
  const int kbeg = ks * (MM / G_KSPLIT);
  const int t = threadIdx.x;
  const int lane = t & 63;
  const int wv = t >> 6;
  const int wr = wv >> 1, wc = wv & 1;

  __shared__ short lA[G_BM * G_BK];
  __shared__ short lB[G_BN * G_BK];

  f32x4 acc[4][4] = {};
  const unsigned short* A  = wts   + (size_t)b * QQ * MM;
  const unsigned short* Bp = projT + (size_t)b * SS * MM;

  for (int k0 = kbeg; k0 < kbeg + MM / G_KSPLIT; k0 += G_BK) {
    __syncthreads();
#pragma unroll
    for (int j = 0; j < 4; ++j) {       // A: 128x64 bf16, 16B per thread per pass
      int e0 = (j * 256 + t) * 8;
      int row = e0 >> 6, k = e0 & 63;
      uint4 src = *reinterpret_cast<const uint4*>(&A[(size_t)(q0 + row) * MM + k0 + k]);
      *reinterpret_cast<uint4*>(&lA[e0 ^ ((row & 7) << 3)]) = src;
    }
#pragma unroll
    for (int j = 0; j < 4; ++j) {       // B: 128x64 bf16
      int e0 = (j * 256 + t) * 8;
      int row = e0 >> 6, k = e0 & 63;
      uint4 src = *reinterpret_cast<const uint4*>(&Bp[(size_t)(s0 + row) * MM + k0 + k]);
      *reinterpret_cast<uint4*>(&lB[e0 ^ ((row & 7) << 3)]) = src;
    }
    __syncthreads();
#pragma unroll
    for (int kk = 0; kk < 2; ++kk) {
      const int kofs = kk * 32 + (lane >> 4) * 8;
      const int r15 = lane & 15;
      bf16x8 af[4], bfv[4];
#pragma unroll
      for (int mi = 0; mi < 4; ++mi) {
        int row = wr * 64 + mi * 16 + r15;
        af[mi] = *reinterpret_cast<const bf16x8*>(&lA[(row * G_BK + kofs) ^ ((row & 7) << 3)]);
      }
#pragma unroll
      for (int ni = 0; ni < 4; ++ni) {
        int row = wc * 64 + ni * 16 + r15;
        bfv[ni] = *reinterpret_cast<const bf16x8*>(&lB[(row * G_BK + kofs) ^ ((row & 7) << 3)]);
      }
#pragma unroll
      for (int mi = 0; mi < 4; ++mi)
#pragma unroll
        for (int ni = 0; ni < 4; ++ni)
          acc[mi][ni] = __builtin_amdgcn_mfma_f32_16x16x32_bf16(af[mi], bfv[ni], acc[mi][ni], 0, 0, 0);
    }
  }

  const int fr = (lane >> 4) * 4;
  const int fc = lane & 15;
#pragma unroll
  for (int mi = 0; mi < 4; ++mi)
#pragma unroll
    for (int ni = 0; ni < 4; ++ni)
#pragma unroll
      for (int r = 0; r < 4; ++r) {
        int q = q0 + wr * 64 + mi * 16 + fr + r;
        int s = s0 + wc * 64 + ni * 16 + fc;
        atomicAdd(&out[(size_t)(b * QQ + q) * SS + s], acc[mi][ni][r]);
      }
}

// ---------------------------------------------------------------------------

extern "C" void kernel_launch(void* const* d_in, const int* in_sizes, int n_in,
                              void* d_out, int out_size, void* d_ws, size_t ws_size,
                              hipStream_t stream) {
  const float* loc    = (const float*)d_in[0];
  const float* locsd  = (const float*)d_in[1];
  const float* mloc   = (const float*)d_in[2];
  const float* msd    = (const float*)d_in[3];
  const float* msense = (const float*)d_in[4];
  const float* wread  = (const float*)d_in[5];
  float* out = (float*)d_out;

  const size_t wts_bytes  = (size_t)BB * QQ * MM * 2;   // 33.5 MB
  const size_t proj_bytes = (size_t)BB * SS * MM * 2;   // 16.8 MB
  if (ws_size < wts_bytes + proj_bytes) return;         // loud failure if ws too small

  unsigned short* wts   = (unsigned short*)d_ws;
  unsigned short* projT = (unsigned short*)((char*)d_ws + wts_bytes);

  hipMemsetAsync(d_out, 0, (size_t)out_size * sizeof(float), stream);

  hipLaunchKernelGGL(k_aff, dim3(BB * QQ / QT), dim3(K1_THREADS), 0, stream,
                     loc, locsd, mloc, msd, wts);
  hipLaunchKernelGGL(k_proj, dim3(MM / P_BN, BB), dim3(512), 0, stream,
                     msense, wread, projT);
  hipLaunchKernelGGL(k_wgemm, dim3(8, G_KSPLIT, BB), dim3(256), 0, stream,
                     wts, projT, out);
}

// Round 2
// 124.366 us; speedup vs baseline: 1.0380x; 1.0380x over previous
//
#include <hip/hip_runtime.h>
#include <hip/hip_bf16.h>

#define BB 4
#define QQ 512
#define MM 8192
#define DD 8
#define EE 512
#define SS 256

using f32x4  = __attribute__((ext_vector_type(4))) float;
using bf16x8 = __attribute__((ext_vector_type(8))) short;

static __device__ __forceinline__ unsigned short f2bf(float f) {
  union { __hip_bfloat16 h; unsigned short u; } v;
  v.h = __float2bfloat16(f);
  return v.u;
}

// ---------------------------------------------------------------------------
// K1: log-affinity (log2 domain) + row max + unnormalized exp2 -> bf16 wts,
//     plus per-row 1/sum -> inv[]  (normalization folded into K3 epilogue).
// la kept in LDS (own-thread slots) to avoid the register-spill disaster.
// ---------------------------------------------------------------------------
#define QT 2
#define K1_T 512
#define K1_I (MM / K1_T)   // 16

__global__ __launch_bounds__(512) void k_aff(
    const float* __restrict__ loc, const float* __restrict__ locsd,
    const float* __restrict__ mloc, const float* __restrict__ msd,
    unsigned short* __restrict__ wts, float* __restrict__ inv)
{
  __shared__ float la_s[QT * K1_I * K1_T];   // 64 KB
  __shared__ float red[QT][8];

  const int blk = blockIdx.x;
  const int b   = blk / (QQ / QT);
  const int q0  = (blk % (QQ / QT)) * QT;
  const int t   = threadIdx.x;
  const int lane = t & 63;
  const int wv   = t >> 6;

  float lx[QT][DD], ls2[QT][DD];
#pragma unroll
  for (int qi = 0; qi < QT; ++qi)
#pragma unroll
    for (int d = 0; d < DD; ++d) {
      const int base = ((b * QQ) + q0 + qi) * DD + d;
      lx[qi][d] = loc[base];
      float s = locsd[base];
      ls2[qi][d] = __builtin_fmaf(s, s, 1e-8f);   // fold eps here (exact)
    }

  const float4* ml4 = reinterpret_cast<const float4*>(mloc + (size_t)b * MM * DD);
  const float4* ms4 = reinterpret_cast<const float4*>(msd  + (size_t)b * MM * DD);

  // lavp = 0.5*log2e*ssum + log2(prod v);  log_aff/ln2 = -lavp + const
  float mn[QT] = {3.4e38f, 3.4e38f};           // track min(lavp) == -max(la2)

#pragma unroll
  for (int i = 0; i < K1_I; ++i) {
    const int m = i * K1_T + t;
    float4 a0 = ml4[2 * m], a1 = ml4[2 * m + 1];
    float4 s0 = ms4[2 * m], s1 = ms4[2 * m + 1];
    float mlv[DD] = {a0.x, a0.y, a0.z, a0.w, a1.x, a1.y, a1.z, a1.w};
    float msv[DD] = {s0.x, s0.y, s0.z, s0.w, s1.x, s1.y, s1.z, s1.w};
    float ms2[DD];
#pragma unroll
    for (int d = 0; d < DD; ++d) ms2[d] = msv[d] * msv[d];
#pragma unroll
    for (int qi = 0; qi < QT; ++qi) {
      float ssum = 0.f, p = 1.f;
#pragma unroll
      for (int d = 0; d < DD; ++d) {
        float v  = ls2[qi][d] + ms2[d];
        float r  = __builtin_amdgcn_rcpf(v);
        float dl = lx[qi][d] - mlv[d];
        float d2 = dl * dl;
        float tt = d2 * r;
        ssum = __builtin_fmaf(tt, tt, ssum);
        p *= v;
      }
      float lavp = __builtin_fmaf(ssum, 0.72134752f, __builtin_amdgcn_logf(p));
      mn[qi] = fminf(mn[qi], lavp);
      la_s[(qi * K1_I + i) * K1_T + t] = lavp;
    }
  }

  // block-wide min(lavp)
#pragma unroll
  for (int qi = 0; qi < QT; ++qi)
#pragma unroll
    for (int off = 32; off; off >>= 1)
      mn[qi] = fminf(mn[qi], __shfl_xor(mn[qi], off, 64));
  if (lane == 0) { red[0][wv] = mn[0]; red[1][wv] = mn[1]; }
  __syncthreads();
  float mnb[QT];
#pragma unroll
  for (int qi = 0; qi < QT; ++qi) {
    float m2 = red[qi][0];
#pragma unroll
    for (int w = 1; w < 8; ++w) m2 = fminf(m2, red[qi][w]);
    mnb[qi] = m2;
  }
  __syncthreads();   // red about to be reused

  float sm[QT] = {0.f, 0.f};
#pragma unroll
  for (int i = 0; i < K1_I; ++i) {
    const int m = i * K1_T + t;
#pragma unroll
    for (int qi = 0; qi < QT; ++qi) {
      float lv = la_s[(qi * K1_I + i) * K1_T + t];
      float e  = __builtin_amdgcn_exp2f(mnb[qi] - lv);   // la2 - max2
      sm[qi] += e;
      wts[((size_t)(b * QQ + q0 + qi)) * MM + m] = f2bf(e);
    }
  }
#pragma unroll
  for (int qi = 0; qi < QT; ++qi)
#pragma unroll
    for (int off = 32; off; off >>= 1)
      sm[qi] += __shfl_xor(sm[qi], off, 64);
  if (lane == 0) { red[0][wv] = sm[0]; red[1][wv] = sm[1]; }
  __syncthreads();
  if (t == 0) {
#pragma unroll
    for (int qi = 0; qi < QT; ++qi) {
      float s = 0.f;
#pragma unroll
      for (int w = 0; w < 8; ++w) s += red[qi][w];
      inv[b * QQ + q0 + qi] = 1.0f / s;
    }
  }
}

// ---------------------------------------------------------------------------
// K2: projT[b][s][m] = sum_e W[s][e] * V[b][m][e]; f32 in, bf16 out.
// 128x128 tile, BK=64, 256 thr (4 waves 2x2), 2-phase reg-staged pipeline.
// ---------------------------------------------------------------------------
__global__ __launch_bounds__(256) void k_proj(
    const float* __restrict__ V, const float* __restrict__ W,
    unsigned short* __restrict__ projT)
{
  const int m0 = blockIdx.x * 128;
  const int s0 = blockIdx.y * 128;
  const int b  = blockIdx.z;
  const int t = threadIdx.x, lane = t & 63, wv = t >> 6;
  const int wr = wv >> 1, wc = wv & 1;

  __shared__ short lA[128 * 64];
  __shared__ short lB[128 * 64];

  f32x4 acc[4][4] = {};

  const float* Wp = W + (size_t)s0 * EE;
  const float* Vp = V + (size_t)b * MM * EE + (size_t)m0 * EE;

  const int r0 = t >> 4;          // 0..15
  const int c0 = (t & 15) * 4;    // float col
  const int swz = (r0 & 7) << 3;

  float4 ra[8], rb[8];

#define P_LOADS(K0)                                                        \
  _Pragma("unroll")                                                        \
  for (int j = 0; j < 8; ++j) {                                            \
    const int row = j * 16 + r0;                                           \
    ra[j] = *reinterpret_cast<const float4*>(&Wp[(size_t)row * EE + (K0) + c0]); \
    rb[j] = *reinterpret_cast<const float4*>(&Vp[(size_t)row * EE + (K0) + c0]); \
  }

  P_LOADS(0)

  for (int ki = 0; ki < 8; ++ki) {
    __syncthreads();
#pragma unroll
    for (int j = 0; j < 8; ++j) {
      const int row = j * 16 + r0;
      const int idx = (row * 64 + c0) ^ swz;
      ushort4 da, db;
      da.x = f2bf(ra[j].x); da.y = f2bf(ra[j].y); da.z = f2bf(ra[j].z); da.w = f2bf(ra[j].w);
      db.x = f2bf(rb[j].x); db.y = f2bf(rb[j].y); db.z = f2bf(rb[j].z); db.w = f2bf(rb[j].w);
      *reinterpret_cast<ushort4*>(&lA[idx]) = da;
      *reinterpret_cast<ushort4*>(&lB[idx]) = db;
    }
    if (ki < 7) { P_LOADS((ki + 1) * 64) }   // in flight under MFMA phase
    __syncthreads();

#pragma unroll
    for (int kk = 0; kk < 2; ++kk) {
      const int kofs = kk * 32 + (lane >> 4) * 8;
      const int r15 = lane & 15;
      bf16x8 af[4], bfv[4];
#pragma unroll
      for (int mi = 0; mi < 4; ++mi) {
        int row = wr * 64 + mi * 16 + r15;
        af[mi] = *reinterpret_cast<const bf16x8*>(&lA[(row * 64 + kofs) ^ ((row & 7) << 3)]);
      }
#pragma unroll
      for (int ni = 0; ni < 4; ++ni) {
        int row = wc * 64 + ni * 16 + r15;
        bfv[ni] = *reinterpret_cast<const bf16x8*>(&lB[(row * 64 + kofs) ^ ((row & 7) << 3)]);
      }
#pragma unroll
      for (int mi = 0; mi < 4; ++mi)
#pragma unroll
        for (int ni = 0; ni < 4; ++ni)
          acc[mi][ni] = __builtin_amdgcn_mfma_f32_16x16x32_bf16(af[mi], bfv[ni], acc[mi][ni], 0, 0, 0);
    }
  }
#undef P_LOADS

  unsigned short* outp = projT + (size_t)b * SS * MM;
  const int fr = (lane >> 4) * 4;
  const int fc = lane & 15;
#pragma unroll
  for (int mi = 0; mi < 4; ++mi)
#pragma unroll
    for (int ni = 0; ni < 4; ++ni)
#pragma unroll
      for (int r = 0; r < 4; ++r) {
        int s = s0 + wr * 64 + mi * 16 + fr + r;
        int m = m0 + wc * 64 + ni * 16 + fc;
        outp[(size_t)s * MM + m] = f2bf(acc[mi][ni][r]);
      }
}

// ---------------------------------------------------------------------------
// K3: out[b][q][s] = inv[q] * sum_m wts[b][q][m] * projT[b][s][m]
// 128x128 tile, BK=64, K-split 16, 2-phase reg-staged pipeline, atomic f32.
// ---------------------------------------------------------------------------
#define KSPLIT 16

__global__ __launch_bounds__(256) void k_wgemm(
    const unsigned short* __restrict__ wts,
    const unsigned short* __restrict__ projT,
    const float* __restrict__ inv,
    float* __restrict__ out)
{
  const int tile = blockIdx.x;          // 0..7 : 4 q-tiles x 2 s-tiles
  const int ks   = blockIdx.y;          // 0..15
  const int b    = blockIdx.z;
  const int q0 = (tile >> 1) * 128;
  const int s0 = (tile & 1) * 128;
  const int kbeg = ks * (MM / KSPLIT);  // *512
  const int t = threadIdx.x, lane = t & 63, wv = t >> 6;
  const int wr = wv >> 1, wc = wv & 1;

  __shared__ short lA[128 * 64];
  __shared__ short lB[128 * 64];

  f32x4 acc[4][4] = {};
  const unsigned short* A  = wts   + (size_t)b * QQ * MM + (size_t)q0 * MM;
  const unsigned short* Bp = projT + (size_t)b * SS * MM + (size_t)s0 * MM;

  const int r0 = t >> 3;        // 0..31
  const int c0 = (t & 7) * 8;   // short col
  const int swz = (r0 & 7) << 3;

  uint4 ua[4], ub[4];

#define G_LOADS(K0)                                                         \
  _Pragma("unroll")                                                         \
  for (int j = 0; j < 4; ++j) {                                             \
    const int row = j * 32 + r0;                                            \
    ua[j] = *reinterpret_cast<const uint4*>(&A[(size_t)row * MM + (K0) + c0]);  \
    ub[j] = *reinterpret_cast<const uint4*>(&Bp[(size_t)row * MM + (K0) + c0]); \
  }

  G_LOADS(kbeg)

  for (int ki = 0; ki < 8; ++ki) {
    __syncthreads();
#pragma unroll
    for (int j = 0; j < 4; ++j) {
      const int row = j * 32 + r0;
      const int idx = (row * 64 + c0) ^ swz;
      *reinterpret_cast<uint4*>(&lA[idx]) = ua[j];
      *reinterpret_cast<uint4*>(&lB[idx]) = ub[j];
    }
    if (ki < 7) { G_LOADS(kbeg + (ki + 1) * 64) }
    __syncthreads();

#pragma unroll
    for (int kk = 0; kk < 2; ++kk) {
      const int kofs = kk * 32 + (lane >> 4) * 8;
      const int r15 = lane & 15;
      bf16x8 af[4], bfv[4];
#pragma unroll
      for (int mi = 0; mi < 4; ++mi) {
        int row = wr * 64 + mi * 16 + r15;
        af[mi] = *reinterpret_cast<const bf16x8*>(&lA[(row * 64 + kofs) ^ ((row & 7) << 3)]);
      }
#pragma unroll
      for (int ni = 0; ni < 4; ++ni) {
        int row = wc * 64 + ni * 16 + r15;
        bfv[ni] = *reinterpret_cast<const bf16x8*>(&lB[(row * 64 + kofs) ^ ((row & 7) << 3)]);
      }
#pragma unroll
      for (int mi = 0; mi < 4; ++mi)
#pragma unroll
        for (int ni = 0; ni < 4; ++ni)
          acc[mi][ni] = __builtin_amdgcn_mfma_f32_16x16x32_bf16(af[mi], bfv[ni], acc[mi][ni], 0, 0, 0);
    }
  }
#undef G_LOADS

  const int fr = (lane >> 4) * 4;
  const int fc = lane & 15;
  const float* invb = inv + b * QQ;
#pragma unroll
  for (int mi = 0; mi < 4; ++mi)
#pragma unroll
    for (int r = 0; r < 4; ++r) {
      const int q = q0 + wr * 64 + mi * 16 + fr + r;
      const float iv = invb[q];
#pragma unroll
      for (int ni = 0; ni < 4; ++ni) {
        const int s = s0 + wc * 64 + ni * 16 + fc;
        atomicAdd(&out[(size_t)(b * QQ + q) * SS + s], acc[mi][ni][r] * iv);
      }
    }
}

// ---------------------------------------------------------------------------

extern "C" void kernel_launch(void* const* d_in, const int* in_sizes, int n_in,
                              void* d_out, int out_size, void* d_ws, size_t ws_size,
                              hipStream_t stream) {
  const float* loc    = (const float*)d_in[0];
  const float* locsd  = (const float*)d_in[1];
  const float* mloc   = (const float*)d_in[2];
  const float* msd    = (const float*)d_in[3];
  const float* msense = (const float*)d_in[4];
  const float* wread  = (const float*)d_in[5];
  float* out = (float*)d_out;

  const size_t wts_bytes  = (size_t)BB * QQ * MM * 2;   // 33.5 MB
  const size_t proj_bytes = (size_t)BB * SS * MM * 2;   // 16.8 MB
  const size_t inv_bytes  = (size_t)BB * QQ * 4;        // 8 KB
  if (ws_size < wts_bytes + proj_bytes + inv_bytes) return;

  unsigned short* wts   = (unsigned short*)d_ws;
  unsigned short* projT = (unsigned short*)((char*)d_ws + wts_bytes);
  float*          inv   = (float*)((char*)d_ws + wts_bytes + proj_bytes);

  hipMemsetAsync(d_out, 0, (size_t)out_size * sizeof(float), stream);

  hipLaunchKernelGGL(k_aff, dim3(BB * QQ / QT), dim3(K1_T), 0, stream,
                     loc, locsd, mloc, msd, wts, inv);
  hipLaunchKernelGGL(k_proj, dim3(MM / 128, SS / 128, BB), dim3(256), 0, stream,
                     msense, wread, projT);
  hipLaunchKernelGGL(k_wgemm, dim3(8, KSPLIT, BB), dim3(256), 0, stream,
                     wts, projT, inv, out);
}

// Round 3
// 108.090 us; speedup vs baseline: 1.1943x; 1.1506x over previous
//
#include <hip/hip_runtime.h>
#include <hip/hip_bf16.h>

#define BB 4
#define QQ 512
#define MM 8192
#define DD 8
#define EE 512
#define SS 256

using f32x4  = __attribute__((ext_vector_type(4))) float;
using bf16x8 = __attribute__((ext_vector_type(8))) short;

static __device__ __forceinline__ unsigned short f2bf(float f) {
  union { __hip_bfloat16 h; unsigned short u; } v;
  v.h = __float2bfloat16(f);
  return v.u;
}

// ---------------------------------------------------------------------------
// K1: log-affinity (log2 domain) + row max + unnormalized exp2 -> bf16 wts,
//     plus per-row 1/sum -> inv[]  (normalization folded into K4 epilogue).
// ---------------------------------------------------------------------------
#define QT 2
#define K1_T 512
#define K1_I (MM / K1_T)   // 16

__global__ __launch_bounds__(512) void k_aff(
    const float* __restrict__ loc, const float* __restrict__ locsd,
    const float* __restrict__ mloc, const float* __restrict__ msd,
    unsigned short* __restrict__ wts, float* __restrict__ inv)
{
  __shared__ float la_s[QT * K1_I * K1_T];   // 64 KB
  __shared__ float red[QT][8];

  const int blk = blockIdx.x;
  const int b   = blk / (QQ / QT);
  const int q0  = (blk % (QQ / QT)) * QT;
  const int t   = threadIdx.x;
  const int lane = t & 63;
  const int wv   = t >> 6;

  float lx[QT][DD], ls2[QT][DD];
#pragma unroll
  for (int qi = 0; qi < QT; ++qi)
#pragma unroll
    for (int d = 0; d < DD; ++d) {
      const int base = ((b * QQ) + q0 + qi) * DD + d;
      lx[qi][d] = loc[base];
      float s = locsd[base];
      ls2[qi][d] = __builtin_fmaf(s, s, 1e-8f);   // fold eps here (exact)
    }

  const float4* ml4 = reinterpret_cast<const float4*>(mloc + (size_t)b * MM * DD);
  const float4* ms4 = reinterpret_cast<const float4*>(msd  + (size_t)b * MM * DD);

  // lavp = 0.5*log2e*ssum + log2(prod v);  log_aff/ln2 = -lavp + const
  float mn[QT] = {3.4e38f, 3.4e38f};           // track min(lavp) == -max(la2)

#pragma unroll
  for (int i = 0; i < K1_I; ++i) {
    const int m = i * K1_T + t;
    float4 a0 = ml4[2 * m], a1 = ml4[2 * m + 1];
    float4 s0 = ms4[2 * m], s1 = ms4[2 * m + 1];
    float mlv[DD] = {a0.x, a0.y, a0.z, a0.w, a1.x, a1.y, a1.z, a1.w};
    float msv[DD] = {s0.x, s0.y, s0.z, s0.w, s1.x, s1.y, s1.z, s1.w};
    float ms2[DD];
#pragma unroll
    for (int d = 0; d < DD; ++d) ms2[d] = msv[d] * msv[d];
#pragma unroll
    for (int qi = 0; qi < QT; ++qi) {
      float ssum = 0.f, p = 1.f;
#pragma unroll
      for (int d = 0; d < DD; ++d) {
        float v  = ls2[qi][d] + ms2[d];
        float r  = __builtin_amdgcn_rcpf(v);
        float dl = lx[qi][d] - mlv[d];
        float d2 = dl * dl;
        float tt = d2 * r;
        ssum = __builtin_fmaf(tt, tt, ssum);
        p *= v;
      }
      float lavp = __builtin_fmaf(ssum, 0.72134752f, __builtin_amdgcn_logf(p));
      mn[qi] = fminf(mn[qi], lavp);
      la_s[(qi * K1_I + i) * K1_T + t] = lavp;
    }
  }

  // block-wide min(lavp)
#pragma unroll
  for (int qi = 0; qi < QT; ++qi)
#pragma unroll
    for (int off = 32; off; off >>= 1)
      mn[qi] = fminf(mn[qi], __shfl_xor(mn[qi], off, 64));
  if (lane == 0) { red[0][wv] = mn[0]; red[1][wv] = mn[1]; }
  __syncthreads();
  float mnb[QT];
#pragma unroll
  for (int qi = 0; qi < QT; ++qi) {
    float m2 = red[qi][0];
#pragma unroll
    for (int w = 1; w < 8; ++w) m2 = fminf(m2, red[qi][w]);
    mnb[qi] = m2;
  }
  __syncthreads();   // red about to be reused

  float sm[QT] = {0.f, 0.f};
#pragma unroll
  for (int i = 0; i < K1_I; ++i) {
    const int m = i * K1_T + t;
#pragma unroll
    for (int qi = 0; qi < QT; ++qi) {
      float lv = la_s[(qi * K1_I + i) * K1_T + t];
      float e  = __builtin_amdgcn_exp2f(mnb[qi] - lv);   // la2 - max2
      sm[qi] += e;
      wts[((size_t)(b * QQ + q0 + qi)) * MM + m] = f2bf(e);
    }
  }
#pragma unroll
  for (int qi = 0; qi < QT; ++qi)
#pragma unroll
    for (int off = 32; off; off >>= 1)
      sm[qi] += __shfl_xor(sm[qi], off, 64);
  if (lane == 0) { red[0][wv] = sm[0]; red[1][wv] = sm[1]; }
  __syncthreads();
  if (t == 0) {
#pragma unroll
    for (int qi = 0; qi < QT; ++qi) {
      float s = 0.f;
#pragma unroll
      for (int w = 0; w < 8; ++w) s += red[qi][w];
      inv[b * QQ + q0 + qi] = 1.0f / s;
    }
  }
}

// ---------------------------------------------------------------------------
// K2: projT[b][s][m] = sum_e W[s][e] * V[b][m][e]; f32 in, bf16 out.
// 128x128 tile, BK=64, 256 thr (4 waves 2x2), 2-phase reg-staged pipeline.
// ---------------------------------------------------------------------------
__global__ __launch_bounds__(256) void k_proj(
    const float* __restrict__ V, const float* __restrict__ W,
    unsigned short* __restrict__ projT)
{
  const int m0 = blockIdx.x * 128;
  const int s0 = blockIdx.y * 128;
  const int b  = blockIdx.z;
  const int t = threadIdx.x, lane = t & 63, wv = t >> 6;
  const int wr = wv >> 1, wc = wv & 1;

  __shared__ short lA[128 * 64];
  __shared__ short lB[128 * 64];

  f32x4 acc[4][4] = {};

  const float* Wp = W + (size_t)s0 * EE;
  const float* Vp = V + (size_t)b * MM * EE + (size_t)m0 * EE;

  const int r0 = t >> 4;          // 0..15
  const int c0 = (t & 15) * 4;    // float col
  const int swz = (r0 & 7) << 3;

  float4 ra[8], rb[8];

#define P_LOADS(K0)                                                        \
  _Pragma("unroll")                                                        \
  for (int j = 0; j < 8; ++j) {                                            \
    const int row = j * 16 + r0;                                           \
    ra[j] = *reinterpret_cast<const float4*>(&Wp[(size_t)row * EE + (K0) + c0]); \
    rb[j] = *reinterpret_cast<const float4*>(&Vp[(size_t)row * EE + (K0) + c0]); \
  }

  P_LOADS(0)

  for (int ki = 0; ki < 8; ++ki) {
    __syncthreads();
#pragma unroll
    for (int j = 0; j < 8; ++j) {
      const int row = j * 16 + r0;
      const int idx = (row * 64 + c0) ^ swz;
      ushort4 da, db;
      da.x = f2bf(ra[j].x); da.y = f2bf(ra[j].y); da.z = f2bf(ra[j].z); da.w = f2bf(ra[j].w);
      db.x = f2bf(rb[j].x); db.y = f2bf(rb[j].y); db.z = f2bf(rb[j].z); db.w = f2bf(rb[j].w);
      *reinterpret_cast<ushort4*>(&lA[idx]) = da;
      *reinterpret_cast<ushort4*>(&lB[idx]) = db;
    }
    if (ki < 7) { P_LOADS((ki + 1) * 64) }   // in flight under MFMA phase
    __syncthreads();

#pragma unroll
    for (int kk = 0; kk < 2; ++kk) {
      const int kofs = kk * 32 + (lane >> 4) * 8;
      const int r15 = lane & 15;
      bf16x8 af[4], bfv[4];
#pragma unroll
      for (int mi = 0; mi < 4; ++mi) {
        int row = wr * 64 + mi * 16 + r15;
        af[mi] = *reinterpret_cast<const bf16x8*>(&lA[(row * 64 + kofs) ^ ((row & 7) << 3)]);
      }
#pragma unroll
      for (int ni = 0; ni < 4; ++ni) {
        int row = wc * 64 + ni * 16 + r15;
        bfv[ni] = *reinterpret_cast<const bf16x8*>(&lB[(row * 64 + kofs) ^ ((row & 7) << 3)]);
      }
#pragma unroll
      for (int mi = 0; mi < 4; ++mi)
#pragma unroll
        for (int ni = 0; ni < 4; ++ni)
          acc[mi][ni] = __builtin_amdgcn_mfma_f32_16x16x32_bf16(af[mi], bfv[ni], acc[mi][ni], 0, 0, 0);
    }
  }
#undef P_LOADS

  unsigned short* outp = projT + (size_t)b * SS * MM;
  const int fr = (lane >> 4) * 4;
  const int fc = lane & 15;
#pragma unroll
  for (int mi = 0; mi < 4; ++mi)
#pragma unroll
    for (int ni = 0; ni < 4; ++ni)
#pragma unroll
      for (int r = 0; r < 4; ++r) {
        int s = s0 + wr * 64 + mi * 16 + fr + r;
        int m = m0 + wc * 64 + ni * 16 + fc;
        outp[(size_t)s * MM + m] = f2bf(acc[mi][ni][r]);
      }
}

// ---------------------------------------------------------------------------
// K3: part[ks][b][q][s] = sum_{m in slice ks} wts[b][q][m] * projT[b][s][m]
// 128x128 tile, BK=64, K-split 8, bf16 partial stores (NO atomics).
// ---------------------------------------------------------------------------
#define KSPLIT 8
#define PSLICE ((size_t)BB * QQ * SS)   // elements per ks slice

__global__ __launch_bounds__(256) void k_wgemm(
    const unsigned short* __restrict__ wts,
    const unsigned short* __restrict__ projT,
    unsigned short* __restrict__ part)
{
  const int tile = blockIdx.x;          // 0..7 : 4 q-tiles x 2 s-tiles
  const int ks   = blockIdx.y;          // 0..7
  const int b    = blockIdx.z;
  const int q0 = (tile >> 1) * 128;
  const int s0 = (tile & 1) * 128;
  const int kbeg = ks * (MM / KSPLIT);  // *1024
  const int t = threadIdx.x, lane = t & 63, wv = t >> 6;
  const int wr = wv >> 1, wc = wv & 1;

  __shared__ short lA[128 * 64];
  __shared__ short lB[128 * 64];

  f32x4 acc[4][4] = {};
  const unsigned short* A  = wts   + (size_t)b * QQ * MM + (size_t)q0 * MM;
  const unsigned short* Bp = projT + (size_t)b * SS * MM + (size_t)s0 * MM;

  const int r0 = t >> 3;        // 0..31
  const int c0 = (t & 7) * 8;   // short col
  const int swz = (r0 & 7) << 3;

  uint4 ua[4], ub[4];

#define G_LOADS(K0)                                                         \
  _Pragma("unroll")                                                         \
  for (int j = 0; j < 4; ++j) {                                             \
    const int row = j * 32 + r0;                                            \
    ua[j] = *reinterpret_cast<const uint4*>(&A[(size_t)row * MM + (K0) + c0]);  \
    ub[j] = *reinterpret_cast<const uint4*>(&Bp[(size_t)row * MM + (K0) + c0]); \
  }

  G_LOADS(kbeg)

  for (int ki = 0; ki < 16; ++ki) {
    __syncthreads();
#pragma unroll
    for (int j = 0; j < 4; ++j) {
      const int row = j * 32 + r0;
      const int idx = (row * 64 + c0) ^ swz;
      *reinterpret_cast<uint4*>(&lA[idx]) = ua[j];
      *reinterpret_cast<uint4*>(&lB[idx]) = ub[j];
    }
    if (ki < 15) { G_LOADS(kbeg + (ki + 1) * 64) }
    __syncthreads();

#pragma unroll
    for (int kk = 0; kk < 2; ++kk) {
      const int kofs = kk * 32 + (lane >> 4) * 8;
      const int r15 = lane & 15;
      bf16x8 af[4], bfv[4];
#pragma unroll
      for (int mi = 0; mi < 4; ++mi) {
        int row = wr * 64 + mi * 16 + r15;
        af[mi] = *reinterpret_cast<const bf16x8*>(&lA[(row * 64 + kofs) ^ ((row & 7) << 3)]);
      }
#pragma unroll
      for (int ni = 0; ni < 4; ++ni) {
        int row = wc * 64 + ni * 16 + r15;
        bfv[ni] = *reinterpret_cast<const bf16x8*>(&lB[(row * 64 + kofs) ^ ((row & 7) << 3)]);
      }
#pragma unroll
      for (int mi = 0; mi < 4; ++mi)
#pragma unroll
        for (int ni = 0; ni < 4; ++ni)
          acc[mi][ni] = __builtin_amdgcn_mfma_f32_16x16x32_bf16(af[mi], bfv[ni], acc[mi][ni], 0, 0, 0);
    }
  }
#undef G_LOADS

  unsigned short* pp = part + (size_t)ks * PSLICE + (size_t)b * QQ * SS;
  const int fr = (lane >> 4) * 4;
  const int fc = lane & 15;
#pragma unroll
  for (int mi = 0; mi < 4; ++mi)
#pragma unroll
    for (int r = 0; r < 4; ++r) {
      const int q = q0 + wr * 64 + mi * 16 + fr + r;
#pragma unroll
      for (int ni = 0; ni < 4; ++ni) {
        const int s = s0 + wc * 64 + ni * 16 + fc;
        pp[(size_t)q * SS + s] = f2bf(acc[mi][ni][r]);
      }
    }
}

// ---------------------------------------------------------------------------
// K4: out[b][q][s] = inv[b][q] * sum_ks part[ks][b][q][s]
// each thread: 2 consecutive s (uint load of 2 bf16), float2 store.
// ---------------------------------------------------------------------------
__global__ __launch_bounds__(256) void k_reduce(
    const unsigned int* __restrict__ part32,
    const float* __restrict__ inv,
    float* __restrict__ out)
{
  const int idx = blockIdx.x * 256 + threadIdx.x;     // pair index
  const int lin = idx * 2;                            // element index
  if (lin >= BB * QQ * SS) return;
  const int qg = lin / SS;                            // b*QQ+q
  float s0 = 0.f, s1 = 0.f;
#pragma unroll
  for (int ks = 0; ks < KSPLIT; ++ks) {
    unsigned int v = part32[ks * (PSLICE / 2) + idx];
    union { unsigned int u; float f; } a, c;
    a.u = (v & 0xffffu) << 16;
    c.u = v & 0xffff0000u;
    s0 += a.f;
    s1 += c.f;
  }
  const float iv = inv[qg];
  float2 o; o.x = s0 * iv; o.y = s1 * iv;
  *reinterpret_cast<float2*>(&out[lin]) = o;
}

// ---------------------------------------------------------------------------

extern "C" void kernel_launch(void* const* d_in, const int* in_sizes, int n_in,
                              void* d_out, int out_size, void* d_ws, size_t ws_size,
                              hipStream_t stream) {
  const float* loc    = (const float*)d_in[0];
  const float* locsd  = (const float*)d_in[1];
  const float* mloc   = (const float*)d_in[2];
  const float* msd    = (const float*)d_in[3];
  const float* msense = (const float*)d_in[4];
  const float* wread  = (const float*)d_in[5];
  float* out = (float*)d_out;

  const size_t wts_bytes  = (size_t)BB * QQ * MM * 2;   // 33.5 MB
  const size_t proj_bytes = (size_t)BB * SS * MM * 2;   // 16.8 MB
  const size_t part_bytes = PSLICE * KSPLIT * 2;        // 8.4 MB
  const size_t inv_bytes  = (size_t)BB * QQ * 4;        // 8 KB
  if (ws_size < wts_bytes + proj_bytes + part_bytes + inv_bytes) return;

  unsigned short* wts   = (unsigned short*)d_ws;
  unsigned short* projT = (unsigned short*)((char*)d_ws + wts_bytes);
  unsigned short* part  = (unsigned short*)((char*)d_ws + wts_bytes + proj_bytes);
  float*          inv   = (float*)((char*)d_ws + wts_bytes + proj_bytes + part_bytes);

  hipLaunchKernelGGL(k_aff, dim3(BB * QQ / QT), dim3(K1_T), 0, stream,
                     loc, locsd, mloc, msd, wts, inv);
  hipLaunchKernelGGL(k_proj, dim3(MM / 128, SS / 128, BB), dim3(256), 0, stream,
                     msense, wread, projT);
  hipLaunchKernelGGL(k_wgemm, dim3(8, KSPLIT, BB), dim3(256), 0, stream,
                     wts, projT, part);
  hipLaunchKernelGGL(k_reduce, dim3((BB * QQ * SS / 2 + 255) / 256), dim3(256), 0, stream,
                     (const unsigned int*)part, inv, out);
}